// Round 1
// baseline (1352.453 us; speedup 1.0000x reference)
//
#include <hip/hip_runtime.h>

typedef __bf16 bf16;
typedef __bf16 bf16x8 __attribute__((ext_vector_type(8)));
typedef float  f32x4  __attribute__((ext_vector_type(4)));

#define EMBED 1024
#define HEADS 16
#define HDIM  64
#define DFF   4096
#define BATCH 4
#define SEQ   2048
#define MROWS 8192   // BATCH*SEQ

// ---------------------------------------------------------------------------
// fp32 -> bf16 elementwise convert (n multiple of 8)
// ---------------------------------------------------------------------------
__global__ __launch_bounds__(256) void cvt_kernel(
    const float* __restrict__ x, bf16* __restrict__ y, int n)
{
  int i = (blockIdx.x * 256 + threadIdx.x) * 8;
  if (i >= n) return;
  float4 a = *(const float4*)(x + i);
  float4 b = *(const float4*)(x + i + 4);
  bf16x8 v;
  v[0] = (bf16)a.x; v[1] = (bf16)a.y; v[2] = (bf16)a.z; v[3] = (bf16)a.w;
  v[4] = (bf16)b.x; v[5] = (bf16)b.y; v[6] = (bf16)b.z; v[7] = (bf16)b.w;
  *(bf16x8*)(y + i) = v;
}

// ---------------------------------------------------------------------------
// Weight transpose-convert: W[K][N] fp32 -> Wt[N][K] bf16. 64x64 tile via LDS.
// ---------------------------------------------------------------------------
__global__ __launch_bounds__(256) void wt_kernel(
    const float* __restrict__ W, bf16* __restrict__ Wt, int K, int N)
{
  __shared__ __align__(16) float Ls[64 * 68];
  const int k0 = blockIdx.x * 64, n0 = blockIdx.y * 64;
  const int ty = threadIdx.x >> 4, tx = threadIdx.x & 15;
  #pragma unroll
  for (int r = 0; r < 4; ++r) {
    const int k = ty + r * 16;
    float4 v = *(const float4*)(W + (size_t)(k0 + k) * N + n0 + tx * 4);
    *(float4*)(Ls + k * 68 + tx * 4) = v;
  }
  __syncthreads();
  #pragma unroll
  for (int it = 0; it < 2; ++it) {
    const int c = it * 256 + threadIdx.x;
    const int n = c >> 3, kc = (c & 7) * 8;
    bf16x8 v;
    #pragma unroll
    for (int j = 0; j < 8; ++j) v[j] = (bf16)Ls[(kc + j) * 68 + n];
    *(bf16x8*)(Wt + (size_t)(n0 + n) * K + k0 + kc) = v;
  }
}

// ---------------------------------------------------------------------------
// bias concat: dst[0:n)=a, [n:2n)=b, [2n:3n)=c (c optional)
// ---------------------------------------------------------------------------
__global__ void cat3_kernel(float* __restrict__ dst, const float* __restrict__ a,
                            const float* __restrict__ b, const float* __restrict__ c, int n)
{
  int i = blockIdx.x * 256 + threadIdx.x;
  if (i < n) dst[i] = a[i];
  else if (i < 2 * n) dst[i] = b[i - n];
  else if (c && i < 3 * n) dst[i] = c[i - 2 * n];
}

// ---------------------------------------------------------------------------
// V transpose for attention: V[(b*Skv+key)*ldv + h*64 + d] ->
// Vt[((b*16+h)*64 + d)*Skv + key].  64key x 64d tile via LDS.
// ---------------------------------------------------------------------------
__global__ __launch_bounds__(256) void vtr_kernel(
    const bf16* __restrict__ V, int ldv, bf16* __restrict__ Vt, int Skv)
{
  __shared__ __align__(16) bf16 Ls[64 * 72];
  const int k0 = blockIdx.x * 64;
  const int bh = blockIdx.y, b = bh >> 4, h = bh & 15;
  const int t = threadIdx.x;
  {
    const int key = t >> 2, dc = (t & 3) * 16;
    const bf16* src = V + (size_t)(b * Skv + k0 + key) * ldv + h * HDIM + dc;
    bf16x8 a0 = *(const bf16x8*)src;
    bf16x8 a1 = *(const bf16x8*)(src + 8);
    *(bf16x8*)(Ls + key * 72 + dc) = a0;
    *(bf16x8*)(Ls + key * 72 + dc + 8) = a1;
  }
  __syncthreads();
  {
    const int d = t >> 2, kc = (t & 3) * 16;
    bf16x8 v0, v1;
    #pragma unroll
    for (int j = 0; j < 8; ++j) v0[j] = Ls[(kc + j) * 72 + d];
    #pragma unroll
    for (int j = 0; j < 8; ++j) v1[j] = Ls[(kc + 8 + j) * 72 + d];
    bf16* dst = Vt + ((size_t)(bh * HDIM + d)) * Skv + k0 + kc;
    *(bf16x8*)dst = v0;
    *(bf16x8*)(dst + 8) = v1;
  }
}

// ---------------------------------------------------------------------------
// 128x128-tile GEMM (m97 structure): C = A @ Bt^T + bias (+res)(+relu)
// A[M][lda], Bt[N][ldb] bf16 (K-contiguous). 2x2 waves, 4x4 accs each.
// global_load_lds width=16 staging; LDS [row][32] unpadded.
// ---------------------------------------------------------------------------
__device__ __forceinline__ void gll16(const bf16* g, bf16* l) {
  __builtin_amdgcn_global_load_lds(
      (const __attribute__((address_space(1))) unsigned*)g,
      (__attribute__((address_space(3))) unsigned*)l, 16, 0, 0);
}

__global__ __launch_bounds__(256) void gemm128(
    const bf16* __restrict__ A, int lda, const bf16* __restrict__ Bt, int ldb,
    const float* __restrict__ bias, const bf16* __restrict__ res_b,
    const float* __restrict__ res_f, bf16* __restrict__ out_b,
    float* __restrict__ out_f, int N, int K, int relu)
{
  __shared__ __align__(16) bf16 As[128 * 32];
  __shared__ __align__(16) bf16 Bs[128 * 32];
  const int tid  = threadIdx.x;
  const int lane = tid & 63, wave = tid >> 6;
  const int quad = lane >> 4, l16 = lane & 15;
  const int wm = wave & 1, wn = wave >> 1;
  const int m0 = blockIdx.y * 128, n0 = blockIdx.x * 128;

  const int c0row = tid >> 2, c0kc = (tid & 3) * 8;
  const int c1row = (256 + tid) >> 2, c1kc = c0kc;

  f32x4 acc[4][4];
  #pragma unroll
  for (int i = 0; i < 4; ++i)
    #pragma unroll
    for (int j = 0; j < 4; ++j) acc[i][j] = f32x4{0, 0, 0, 0};

  for (int k0 = 0; k0 < K; k0 += 32) {
    gll16(A  + (size_t)(m0 + c0row) * lda + k0 + c0kc, As + (size_t)(wave * 64) * 8);
    gll16(Bt + (size_t)(n0 + c0row) * ldb + k0 + c0kc, Bs + (size_t)(wave * 64) * 8);
    gll16(A  + (size_t)(m0 + c1row) * lda + k0 + c1kc, As + (size_t)(256 + wave * 64) * 8);
    gll16(Bt + (size_t)(n0 + c1row) * ldb + k0 + c1kc, Bs + (size_t)(256 + wave * 64) * 8);
    __syncthreads();

    bf16x8 af[4], bfr[4];
    #pragma unroll
    for (int i = 0; i < 4; ++i)
      af[i] = *(const bf16x8*)(As + (wm * 64 + i * 16 + l16) * 32 + quad * 8);
    #pragma unroll
    for (int j = 0; j < 4; ++j)
      bfr[j] = *(const bf16x8*)(Bs + (wn * 64 + j * 16 + l16) * 32 + quad * 8);
    #pragma unroll
    for (int i = 0; i < 4; ++i)
      #pragma unroll
      for (int j = 0; j < 4; ++j)
        acc[i][j] = __builtin_amdgcn_mfma_f32_16x16x32_bf16(af[i], bfr[j], acc[i][j], 0, 0, 0);
    __syncthreads();
  }

  #pragma unroll
  for (int j = 0; j < 4; ++j) {
    const int col = n0 + wn * 64 + j * 16 + l16;
    const float bv = bias ? bias[col] : 0.f;
    #pragma unroll
    for (int i = 0; i < 4; ++i) {
      #pragma unroll
      for (int r = 0; r < 4; ++r) {
        const int row = m0 + wm * 64 + i * 16 + quad * 4 + r;
        const size_t idx = (size_t)row * N + col;
        float v = acc[i][j][r] + bv;
        if (res_b) v += (float)res_b[idx];
        if (res_f) v += res_f[idx];
        if (relu)  v = fmaxf(v, 0.f);
        if (out_b) out_b[idx] = (bf16)v;
        if (out_f) out_f[idx] = v;
      }
    }
  }
}

// ---------------------------------------------------------------------------
// LayerNorm over last dim (1024): fp32 in, fp32 params, bf16 and/or fp32 out.
// ---------------------------------------------------------------------------
__global__ __launch_bounds__(256) void ln_kernel(
    const float* __restrict__ x, const float* __restrict__ g, const float* __restrict__ b,
    bf16* __restrict__ out_b, float* __restrict__ out_f)
{
  __shared__ float red[8];
  const int tid = threadIdx.x, lane = tid & 63, wave = tid >> 6;
  const float* xr = x + (size_t)blockIdx.x * EMBED;
  float4 v = *(const float4*)(xr + tid * 4);
  float vv[4] = {v.x, v.y, v.z, v.w};
  float s  = vv[0] + vv[1] + vv[2] + vv[3];
  float s2 = vv[0]*vv[0] + vv[1]*vv[1] + vv[2]*vv[2] + vv[3]*vv[3];
  #pragma unroll
  for (int off = 32; off >= 1; off >>= 1) {
    s  += __shfl_xor(s, off);
    s2 += __shfl_xor(s2, off);
  }
  if (lane == 0) { red[wave] = s; red[4 + wave] = s2; }
  __syncthreads();
  s  = red[0] + red[1] + red[2] + red[3];
  s2 = red[4] + red[5] + red[6] + red[7];
  const float mu  = s * (1.f / EMBED);
  const float var = s2 * (1.f / EMBED) - mu * mu;
  const float rs  = rsqrtf(fmaxf(var, 0.f) + 1e-5f);
  #pragma unroll
  for (int i = 0; i < 4; ++i) {
    const int col = tid * 4 + i;
    const float o = (vv[i] - mu) * rs * g[col] + b[col];
    const size_t idx = (size_t)blockIdx.x * EMBED + col;
    if (out_b) out_b[idx] = (bf16)o;
    if (out_f) out_f[idx] = o;
  }
}

// ---------------------------------------------------------------------------
// MFMA flash attention, 128-q tile per block (4 waves x 2 m-tiles), 64-key
// K-tiles.  K/V staged via global_load_lds into linear [row][64] tiles
// (128 B rows) with a 16-B-granule XOR swizzle applied on the SOURCE address
// (rule #21: linear DMA dest + inverse-swizzled source + swizzled read).
// Double-buffered: tile t+1's 4 gll calls issue before tile t's compute, so
// the trailing __syncthreads' vmcnt(0) drain lands after ~1000 cy of compute
// has hidden the load latency.  One barrier per K-tile (was two).
// Online softmax in registers (unchanged math).
// ---------------------------------------------------------------------------
__global__ __launch_bounds__(256) void fattn_kernel(
    const bf16* __restrict__ Q, int ldq, const bf16* __restrict__ K, int ldk,
    const bf16* __restrict__ Vt, bf16* __restrict__ Y, int Skv, int causal)
{
  constexpr int PLD = 72;                       // P-buffer stride (conflict-free)
  __shared__ __align__(16) bf16 Ks[2][64 * 64]; // [key][d], swizzled
  __shared__ __align__(16) bf16 Vs[2][64 * 64]; // [d][key], swizzled
  __shared__ __align__(16) bf16 Ps[4 * 32 * PLD];

  const int tid  = threadIdx.x;
  const int lane = tid & 63, wave = tid >> 6;
  const int quad = lane >> 4, l16 = lane & 15;
  const int q0 = blockIdx.x * 128;
  const int bh = blockIdx.y, b = bh >> 4, h = bh & 15;
  const int wq0 = q0 + wave * 32;

  const bf16* Kb = K + (size_t)b * Skv * ldk + h * HDIM;
  const bf16* Vb = Vt + (size_t)(bh * HDIM) * Skv;

  // staging lane geometry: lane l -> row r0+c*8+(l>>3), dest 16B-block (l&7);
  // source block = dest ^ (row&7)  (row&7 == l>>3 since r0,c*8 are mult. of 8)
  const int sr = lane >> 3;
  const int se = ((lane & 7) ^ sr) << 3;        // swizzled source elem offset

  // swizzled read offsets (row&7 == l16&7 since nt*16 is a multiple of 8)
  const int sw  = l16 & 7;
  const int co0 = (quad ^ sw) << 3;             // block quad   -> elems quad*8
  const int co1 = ((4 + quad) ^ sw) << 3;       // block 4+quad -> elems 32+quad*8

  auto stage = [&](int kt, int buf) {
    const int k0 = kt * 64;
    const int r0 = wave * 16;
    gll16(Kb + (size_t)(k0 + r0 + sr) * ldk + se,     &Ks[buf][(r0)     * 64]);
    gll16(Kb + (size_t)(k0 + r0 + 8 + sr) * ldk + se, &Ks[buf][(r0 + 8) * 64]);
    gll16(Vb + (size_t)(r0 + sr) * Skv + k0 + se,     &Vs[buf][(r0)     * 64]);
    gll16(Vb + (size_t)(r0 + 8 + sr) * Skv + k0 + se, &Vs[buf][(r0 + 8) * 64]);
  };

  bf16x8 qf[2][2];
  #pragma unroll
  for (int i = 0; i < 2; ++i) {
    const bf16* qp = Q + (size_t)(b * SEQ + wq0 + i * 16 + l16) * ldq + h * HDIM;
    qf[i][0] = *(const bf16x8*)(qp + quad * 8);
    qf[i][1] = *(const bf16x8*)(qp + 32 + quad * 8);
  }

  f32x4 O[2][4];
  float m_run[2][4], l_run[2][4];
  #pragma unroll
  for (int i = 0; i < 2; ++i)
    #pragma unroll
    for (int nt = 0; nt < 4; ++nt) O[i][nt] = f32x4{0, 0, 0, 0};
  #pragma unroll
  for (int i = 0; i < 2; ++i)
    #pragma unroll
    for (int r = 0; r < 4; ++r) { m_run[i][r] = -1e30f; l_run[i][r] = 0.f; }

  bf16* Pw = Ps + wave * 32 * PLD;
  const int nkt = causal ? (q0 / 64 + 2) : (Skv / 64);

  stage(0, 0);
  __syncthreads();          // tile 0 landed (vmcnt(0) + barrier)

  for (int kt = 0; kt < nkt; ++kt) {
    const int cur = kt & 1;
    const int k0 = kt * 64;
    if (kt + 1 < nkt) stage(kt + 1, cur ^ 1);   // prefetch overlaps compute

    const bf16* Kc = Ks[cur];
    const bf16* Vc = Vs[cur];

    // ---- S = Q K^T ----
    f32x4 s[2][4];
    __builtin_amdgcn_s_setprio(1);
    #pragma unroll
    for (int nt = 0; nt < 4; ++nt) {
      const int row = nt * 16 + l16;
      bf16x8 kf0 = *(const bf16x8*)(Kc + row * 64 + co0);
      bf16x8 kf1 = *(const bf16x8*)(Kc + row * 64 + co1);
      #pragma unroll
      for (int i = 0; i < 2; ++i) {
        f32x4 t = f32x4{0, 0, 0, 0};
        t = __builtin_amdgcn_mfma_f32_16x16x32_bf16(qf[i][0], kf0, t, 0, 0, 0);
        t = __builtin_amdgcn_mfma_f32_16x16x32_bf16(qf[i][1], kf1, t, 0, 0, 0);
        s[i][nt] = t;
      }
    }
    __builtin_amdgcn_s_setprio(0);

    const bool diag = causal && (k0 + 63 > wq0);
    #pragma unroll
    for (int i = 0; i < 2; ++i) {
      #pragma unroll
      for (int nt = 0; nt < 4; ++nt) {
        const int key = k0 + nt * 16 + l16;
        #pragma unroll
        for (int r = 0; r < 4; ++r) {
          float v = s[i][nt][r] * 0.125f;          // 1/sqrt(64)
          const int q = wq0 + i * 16 + quad * 4 + r;
          if (diag && key > q) v = -1e30f;
          s[i][nt][r] = v;
        }
      }
    }

    // ---- online softmax + P store + O rescale ----
    #pragma unroll
    for (int i = 0; i < 2; ++i) {
      float rm[4], al[4], ls[4];
      #pragma unroll
      for (int r = 0; r < 4; ++r)
        rm[r] = fmaxf(fmaxf(s[i][0][r], s[i][1][r]), fmaxf(s[i][2][r], s[i][3][r]));
      #pragma unroll
      for (int off = 1; off < 16; off <<= 1) {
        #pragma unroll
        for (int r = 0; r < 4; ++r) rm[r] = fmaxf(rm[r], __shfl_xor(rm[r], off));
      }
      #pragma unroll
      for (int r = 0; r < 4; ++r) {
        const float m_new = fmaxf(m_run[i][r], rm[r]);
        al[r] = __expf(m_run[i][r] - m_new);
        m_run[i][r] = m_new;
      }
      #pragma unroll
      for (int nt = 0; nt < 4; ++nt)
        #pragma unroll
        for (int r = 0; r < 4; ++r)
          s[i][nt][r] = __expf(s[i][nt][r] - m_run[i][r]);
      #pragma unroll
      for (int r = 0; r < 4; ++r)
        ls[r] = s[i][0][r] + s[i][1][r] + s[i][2][r] + s[i][3][r];
      #pragma unroll
      for (int off = 1; off < 16; off <<= 1) {
        #pragma unroll
        for (int r = 0; r < 4; ++r) ls[r] += __shfl_xor(ls[r], off);
      }
      #pragma unroll
      for (int r = 0; r < 4; ++r) l_run[i][r] = l_run[i][r] * al[r] + ls[r];
      #pragma unroll
      for (int nt = 0; nt < 4; ++nt) {
        #pragma unroll
        for (int r = 0; r < 4; ++r)
          Pw[(i * 16 + quad * 4 + r) * PLD + nt * 16 + l16] = (bf16)s[i][nt][r];
        #pragma unroll
        for (int r = 0; r < 4; ++r) O[i][nt][r] *= al[r];
      }
    }

    // ---- O += P V ----
    bf16x8 pf[2][2];
    #pragma unroll
    for (int i = 0; i < 2; ++i) {
      pf[i][0] = *(const bf16x8*)(Pw + (i * 16 + l16) * PLD + quad * 8);
      pf[i][1] = *(const bf16x8*)(Pw + (i * 16 + l16) * PLD + 32 + quad * 8);
    }
    __builtin_amdgcn_s_setprio(1);
    #pragma unroll
    for (int nt = 0; nt < 4; ++nt) {
      const int row = nt * 16 + l16;
      bf16x8 vf0 = *(const bf16x8*)(Vc + row * 64 + co0);
      bf16x8 vf1 = *(const bf16x8*)(Vc + row * 64 + co1);
      #pragma unroll
      for (int i = 0; i < 2; ++i) {
        O[i][nt] = __builtin_amdgcn_mfma_f32_16x16x32_bf16(pf[i][0], vf0, O[i][nt], 0, 0, 0);
        O[i][nt] = __builtin_amdgcn_mfma_f32_16x16x32_bf16(pf[i][1], vf1, O[i][nt], 0, 0, 0);
      }
    }
    __builtin_amdgcn_s_setprio(0);
    __syncthreads();        // all reads of buf[cur] done; next-tile DMA drained
  }

  #pragma unroll
  for (int i = 0; i < 2; ++i) {
    float inv[4];
    #pragma unroll
    for (int r = 0; r < 4; ++r) inv[r] = 1.f / l_run[i][r];
    #pragma unroll
    for (int nt = 0; nt < 4; ++nt) {
      #pragma unroll
      for (int r = 0; r < 4; ++r) {
        const int q = wq0 + i * 16 + quad * 4 + r;
        Y[((size_t)(b * SEQ + q)) * EMBED + h * HDIM + nt * 16 + l16] = (bf16)(O[i][nt][r] * inv[r]);
      }
    }
  }
}

__global__ void fill_kernel(float* out, float v, int n) {
  int i = blockIdx.x * 256 + threadIdx.x;
  if (i < n) out[i] = v;
}

// ---------------------------------------------------------------------------
extern "C" void kernel_launch(void* const* d_in, const int* in_sizes, int n_in,
                              void* d_out, int out_size, void* d_ws, size_t ws_size,
                              hipStream_t stream)
{
  const float* tgt    = (const float*)d_in[0];
  const float* mem    = (const float*)d_in[1];
  const float* sa_Wq  = (const float*)d_in[3];
  const float* sa_Wqb = (const float*)d_in[4];
  const float* sa_Wk  = (const float*)d_in[5];
  const float* sa_Wkb = (const float*)d_in[6];
  const float* sa_Wv  = (const float*)d_in[7];
  const float* sa_Wvb = (const float*)d_in[8];
  const float* sa_A   = (const float*)d_in[9];
  const float* sa_Ab  = (const float*)d_in[10];
  const float* ca_Wq  = (const float*)d_in[11];
  const float* ca_Wqb = (const float*)d_in[12];
  const float* ca_Wk  = (const float*)d_in[13];
  const float* ca_Wkb = (const float*)d_in[14];
  const float* ca_Wv  = (const float*)d_in[15];
  const float* ca_Wvb = (const float*)d_in[16];
  const float* ca_A   = (const float*)d_in[17];
  const float* ca_Ab  = (const float*)d_in[18];
  const float* l1W    = (const float*)d_in[19];
  const float* l1b    = (const float*)d_in[20];
  const float* l2W    = (const float*)d_in[21];
  const float* l2b    = (const float*)d_in[22];
  const float* g1     = (const float*)d_in[23];
  const float* b1     = (const float*)d_in[24];
  const float* g2     = (const float*)d_in[25];
  const float* b2     = (const float*)d_in[26];
  const float* g3     = (const float*)d_in[27];
  const float* b3     = (const float*)d_in[28];

  const size_t MB = 1024 * 1024;
  const size_t NEED = 80 * MB + 4096;
  if (ws_size < NEED) {
    fill_kernel<<<(out_size + 255) / 256, 256, 0, stream>>>((float*)d_out, 3.0f, out_size);
    return;
  }

  char* ws = (char*)d_ws;
  const size_t MD = (size_t)MROWS * EMBED;       // 8M elements
  // phase A
  bf16*  qkv   = (bf16*)ws;                      // [8192][3072] 48 MB
  bf16*  yb    = (bf16*)(ws + 48 * MB);          // 16 MB attention output
  bf16*  wqkvt = (bf16*)(ws + 48 * MB);          // 6 MB weights (dead before fattn writes yb)
  float* qkvbias = (float*)(ws + 54 * MB + 512 * 1024);
  // phase B
  bf16*  kvb   = (bf16*)ws;                      // [8192][2048] 32 MB
  bf16*  qB    = (bf16*)(ws + 32 * MB);          // 16 MB
  bf16*  wkvt  = (bf16*)(ws + 48 * MB);          // 4 MB
  bf16*  wqt   = (bf16*)(ws + 52 * MB);          // 2 MB
  float* kvbias = (float*)(ws + 54 * MB + 512 * 1024);
  // shared
  bf16*  awt   = (bf16*)ws;                      // 2 MB out-proj Wt (qkv/kvb dead)
  bf16*  xb    = (bf16*)(ws + 64 * MB);          // 16 MB LN output stream
  // phase C
  bf16*  hb    = (bf16*)ws;                      // [8192][2048] 32 MB hidden half
  bf16*  l1t   = (bf16*)(ws + 32 * MB);          // 8 MB
  bf16*  l2t   = (bf16*)(ws + 40 * MB);          // 8 MB
  // d_out regions
  float* P   = (float*)d_out;                    // fp32 pre-LN scratch (32 MB)
  bf16*  inb = (bf16*)d_out;                     // converted tgt/mem (16 MB)
  bf16*  vtg = (bf16*)((char*)d_out + 16 * MB);  // V^T for attention (16 MB)

  dim3 blk(256);
  dim3 gQKV(3072 / 128, MROWS / 128);   // (24,64)
  dim3 gKV(2048 / 128, MROWS / 128);    // (16,64)
  dim3 gEE(EMBED / 128, MROWS / 128);   // (8,64)
  dim3 gF1(2048 / 128, MROWS / 128);    // (16,64)
  dim3 gAT(SEQ / 128, BATCH * HEADS);   // (16,64)
  dim3 gVT(SEQ / 64, BATCH * HEADS);    // (32,64)
  dim3 gWee(16, 16);
  const int ncv = (int)(MD / 8 / 256);

  // ---- Phase A: self-attention ----
  cvt_kernel<<<ncv, blk, 0, stream>>>(tgt, inb, (int)MD);
  wt_kernel<<<gWee, blk, 0, stream>>>(sa_Wq, wqkvt, EMBED, EMBED);
  wt_kernel<<<gWee, blk, 0, stream>>>(sa_Wk, wqkvt + 1024 * 1024, EMBED, EMBED);
  wt_kernel<<<gWee, blk, 0, stream>>>(sa_Wv, wqkvt + 2 * 1024 * 1024, EMBED, EMBED);
  cat3_kernel<<<12, blk, 0, stream>>>(qkvbias, sa_Wqb, sa_Wkb, sa_Wvb, EMBED);
  gemm128<<<gQKV, blk, 0, stream>>>(inb, EMBED, wqkvt, EMBED, qkvbias, nullptr, nullptr, qkv, nullptr, 3072, EMBED, 0);
  vtr_kernel<<<gVT, blk, 0, stream>>>(qkv + 2048, 3072, vtg, SEQ);
  fattn_kernel<<<gAT, blk, 0, stream>>>(qkv, 3072, qkv + 1024, 3072, vtg, yb, SEQ, 1);
  wt_kernel<<<gWee, blk, 0, stream>>>(sa_A, awt, EMBED, EMBED);
  gemm128<<<gEE, blk, 0, stream>>>(yb, EMBED, awt, EMBED, sa_Ab, nullptr, tgt, nullptr, P, EMBED, EMBED, 0);
  ln_kernel<<<MROWS, blk, 0, stream>>>(P, g1, b1, xb, nullptr);

  // ---- Phase B: cross-attention ----
  cvt_kernel<<<ncv, blk, 0, stream>>>(mem, inb, (int)MD);
  wt_kernel<<<gWee, blk, 0, stream>>>(ca_Wk, wkvt, EMBED, EMBED);
  wt_kernel<<<gWee, blk, 0, stream>>>(ca_Wv, wkvt + 1024 * 1024, EMBED, EMBED);
  wt_kernel<<<gWee, blk, 0, stream>>>(ca_Wq, wqt, EMBED, EMBED);
  cat3_kernel<<<8, blk, 0, stream>>>(kvbias, ca_Wkb, ca_Wvb, nullptr, EMBED);
  gemm128<<<gKV, blk, 0, stream>>>(inb, EMBED, wkvt, EMBED, kvbias, nullptr, nullptr, kvb, nullptr, 2048, EMBED, 0);
  gemm128<<<gEE, blk, 0, stream>>>(xb, EMBED, wqt, EMBED, ca_Wqb, nullptr, nullptr, qB, nullptr, EMBED, EMBED, 0);
  vtr_kernel<<<gVT, blk, 0, stream>>>(kvb + 1024, 2048, vtg, SEQ);
  fattn_kernel<<<gAT, blk, 0, stream>>>(qB, 1024, kvb, 2048, vtg, yb, SEQ, 0);
  wt_kernel<<<gWee, blk, 0, stream>>>(ca_A, awt, EMBED, EMBED);
  gemm128<<<gEE, blk, 0, stream>>>(yb, EMBED, awt, EMBED, ca_Ab, xb, nullptr, nullptr, P, EMBED, EMBED, 0);
  ln_kernel<<<MROWS, blk, 0, stream>>>(P, g2, b2, xb, nullptr);

  // ---- Phase C: FFN (split-K over DFF halves) ----
  wt_kernel<<<dim3(16, 64), blk, 0, stream>>>(l1W, l1t, EMBED, DFF);
  wt_kernel<<<dim3(64, 16), blk, 0, stream>>>(l2W, l2t, DFF, EMBED);
  gemm128<<<gF1, blk, 0, stream>>>(xb, EMBED, l1t, EMBED, l1b, nullptr, nullptr, hb, nullptr, 2048, EMBED, 1);
  gemm128<<<gEE, blk, 0, stream>>>(hb, 2048, l2t, DFF, l2b, xb, nullptr, nullptr, P, EMBED, 2048, 0);
  gemm128<<<gF1, blk, 0, stream>>>(xb, EMBED, l1t + (size_t)2048 * 1024, EMBED, l1b + 2048, nullptr, nullptr, hb, nullptr, 2048, EMBED, 1);
  gemm128<<<gEE, blk, 0, stream>>>(hb, 2048, l2t + 2048, DFF, nullptr, nullptr, P, nullptr, P, EMBED, 2048, 0);
  ln_kernel<<<MROWS, blk, 0, stream>>>(P, g3, b3, nullptr, (float*)d_out);
}

// Round 2
// 1202.893 us; speedup vs baseline: 1.1243x; 1.1243x over previous
//
#include <hip/hip_runtime.h>

typedef __bf16 bf16;
typedef __bf16 bf16x4 __attribute__((ext_vector_type(4)));
typedef __bf16 bf16x8 __attribute__((ext_vector_type(8)));
typedef float  f32x4  __attribute__((ext_vector_type(4)));

#define EMBED 1024
#define HEADS 16
#define HDIM  64
#define DFF   4096
#define BATCH 4
#define SEQ   2048
#define MROWS 8192   // BATCH*SEQ

// ---------------------------------------------------------------------------
// fp32 -> bf16 elementwise convert (n multiple of 8)
// ---------------------------------------------------------------------------
__global__ __launch_bounds__(256) void cvt_kernel(
    const float* __restrict__ x, bf16* __restrict__ y, int n)
{
  int i = (blockIdx.x * 256 + threadIdx.x) * 8;
  if (i >= n) return;
  float4 a = *(const float4*)(x + i);
  float4 b = *(const float4*)(x + i + 4);
  bf16x8 v;
  v[0] = (bf16)a.x; v[1] = (bf16)a.y; v[2] = (bf16)a.z; v[3] = (bf16)a.w;
  v[4] = (bf16)b.x; v[5] = (bf16)b.y; v[6] = (bf16)b.z; v[7] = (bf16)b.w;
  *(bf16x8*)(y + i) = v;
}

// ---------------------------------------------------------------------------
// Weight transpose-convert: W[K][N] fp32 -> Wt[N][K] bf16. 64x64 tile via LDS.
// ---------------------------------------------------------------------------
__global__ __launch_bounds__(256) void wt_kernel(
    const float* __restrict__ W, bf16* __restrict__ Wt, int K, int N)
{
  __shared__ __align__(16) float Ls[64 * 68];
  const int k0 = blockIdx.x * 64, n0 = blockIdx.y * 64;
  const int ty = threadIdx.x >> 4, tx = threadIdx.x & 15;
  #pragma unroll
  for (int r = 0; r < 4; ++r) {
    const int k = ty + r * 16;
    float4 v = *(const float4*)(W + (size_t)(k0 + k) * N + n0 + tx * 4);
    *(float4*)(Ls + k * 68 + tx * 4) = v;
  }
  __syncthreads();
  #pragma unroll
  for (int it = 0; it < 2; ++it) {
    const int c = it * 256 + threadIdx.x;
    const int n = c >> 3, kc = (c & 7) * 8;
    bf16x8 v;
    #pragma unroll
    for (int j = 0; j < 8; ++j) v[j] = (bf16)Ls[(kc + j) * 68 + n];
    *(bf16x8*)(Wt + (size_t)(n0 + n) * K + k0 + kc) = v;
  }
}

// ---------------------------------------------------------------------------
// bias concat: dst[0:n)=a, [n:2n)=b, [2n:3n)=c (c optional)
// ---------------------------------------------------------------------------
__global__ void cat3_kernel(float* __restrict__ dst, const float* __restrict__ a,
                            const float* __restrict__ b, const float* __restrict__ c, int n)
{
  int i = blockIdx.x * 256 + threadIdx.x;
  if (i < n) dst[i] = a[i];
  else if (i < 2 * n) dst[i] = b[i - n];
  else if (c && i < 3 * n) dst[i] = c[i - 2 * n];
}

// ---------------------------------------------------------------------------
// V transpose for attention: V[(b*Skv+key)*ldv + h*64 + d] ->
// Vt[((b*16+h)*64 + d)*Skv + key].  64key x 64d tile via LDS.
// ---------------------------------------------------------------------------
__global__ __launch_bounds__(256) void vtr_kernel(
    const bf16* __restrict__ V, int ldv, bf16* __restrict__ Vt, int Skv)
{
  __shared__ __align__(16) bf16 Ls[64 * 72];
  const int k0 = blockIdx.x * 64;
  const int bh = blockIdx.y, b = bh >> 4, h = bh & 15;
  const int t = threadIdx.x;
  {
    const int key = t >> 2, dc = (t & 3) * 16;
    const bf16* src = V + (size_t)(b * Skv + k0 + key) * ldv + h * HDIM + dc;
    bf16x8 a0 = *(const bf16x8*)src;
    bf16x8 a1 = *(const bf16x8*)(src + 8);
    *(bf16x8*)(Ls + key * 72 + dc) = a0;
    *(bf16x8*)(Ls + key * 72 + dc + 8) = a1;
  }
  __syncthreads();
  {
    const int d = t >> 2, kc = (t & 3) * 16;
    bf16x8 v0, v1;
    #pragma unroll
    for (int j = 0; j < 8; ++j) v0[j] = Ls[(kc + j) * 72 + d];
    #pragma unroll
    for (int j = 0; j < 8; ++j) v1[j] = Ls[(kc + 8 + j) * 72 + d];
    bf16* dst = Vt + ((size_t)(bh * HDIM + d)) * Skv + k0 + kc;
    *(bf16x8*)dst = v0;
    *(bf16x8*)(dst + 8) = v1;
  }
}

// ---------------------------------------------------------------------------
// 128x128-tile GEMM (m97 structure): C = A @ Bt^T + bias (+res)(+relu)
// A[M][lda], Bt[N][ldb] bf16 (K-contiguous). 2x2 waves, 4x4 accs each.
// global_load_lds width=16 staging; LDS [row][32] unpadded.
// ---------------------------------------------------------------------------
__device__ __forceinline__ void gll16(const bf16* g, bf16* l) {
  __builtin_amdgcn_global_load_lds(
      (const __attribute__((address_space(1))) unsigned*)g,
      (__attribute__((address_space(3))) unsigned*)l, 16, 0, 0);
}

__global__ __launch_bounds__(256) void gemm128(
    const bf16* __restrict__ A, int lda, const bf16* __restrict__ Bt, int ldb,
    const float* __restrict__ bias, const bf16* __restrict__ res_b,
    const float* __restrict__ res_f, bf16* __restrict__ out_b,
    float* __restrict__ out_f, int N, int K, int relu)
{
  __shared__ __align__(16) bf16 As[128 * 32];
  __shared__ __align__(16) bf16 Bs[128 * 32];
  const int tid  = threadIdx.x;
  const int lane = tid & 63, wave = tid >> 6;
  const int quad = lane >> 4, l16 = lane & 15;
  const int wm = wave & 1, wn = wave >> 1;
  const int m0 = blockIdx.y * 128, n0 = blockIdx.x * 128;

  const int c0row = tid >> 2, c0kc = (tid & 3) * 8;
  const int c1row = (256 + tid) >> 2, c1kc = c0kc;

  f32x4 acc[4][4];
  #pragma unroll
  for (int i = 0; i < 4; ++i)
    #pragma unroll
    for (int j = 0; j < 4; ++j) acc[i][j] = f32x4{0, 0, 0, 0};

  for (int k0 = 0; k0 < K; k0 += 32) {
    gll16(A  + (size_t)(m0 + c0row) * lda + k0 + c0kc, As + (size_t)(wave * 64) * 8);
    gll16(Bt + (size_t)(n0 + c0row) * ldb + k0 + c0kc, Bs + (size_t)(wave * 64) * 8);
    gll16(A  + (size_t)(m0 + c1row) * lda + k0 + c1kc, As + (size_t)(256 + wave * 64) * 8);
    gll16(Bt + (size_t)(n0 + c1row) * ldb + k0 + c1kc, Bs + (size_t)(256 + wave * 64) * 8);
    __syncthreads();

    bf16x8 af[4], bfr[4];
    #pragma unroll
    for (int i = 0; i < 4; ++i)
      af[i] = *(const bf16x8*)(As + (wm * 64 + i * 16 + l16) * 32 + quad * 8);
    #pragma unroll
    for (int j = 0; j < 4; ++j)
      bfr[j] = *(const bf16x8*)(Bs + (wn * 64 + j * 16 + l16) * 32 + quad * 8);
    #pragma unroll
    for (int i = 0; i < 4; ++i)
      #pragma unroll
      for (int j = 0; j < 4; ++j)
        acc[i][j] = __builtin_amdgcn_mfma_f32_16x16x32_bf16(af[i], bfr[j], acc[i][j], 0, 0, 0);
    __syncthreads();
  }

  #pragma unroll
  for (int j = 0; j < 4; ++j) {
    const int col = n0 + wn * 64 + j * 16 + l16;
    const float bv = bias ? bias[col] : 0.f;
    #pragma unroll
    for (int i = 0; i < 4; ++i) {
      #pragma unroll
      for (int r = 0; r < 4; ++r) {
        const int row = m0 + wm * 64 + i * 16 + quad * 4 + r;
        const size_t idx = (size_t)row * N + col;
        float v = acc[i][j][r] + bv;
        if (res_b) v += (float)res_b[idx];
        if (res_f) v += res_f[idx];
        if (relu)  v = fmaxf(v, 0.f);
        if (out_b) out_b[idx] = (bf16)v;
        if (out_f) out_f[idx] = v;
      }
    }
  }
}

// ---------------------------------------------------------------------------
// LayerNorm over last dim (1024): fp32 in, fp32 params, bf16 and/or fp32 out.
// ---------------------------------------------------------------------------
__global__ __launch_bounds__(256) void ln_kernel(
    const float* __restrict__ x, const float* __restrict__ g, const float* __restrict__ b,
    bf16* __restrict__ out_b, float* __restrict__ out_f)
{
  __shared__ float red[8];
  const int tid = threadIdx.x, lane = tid & 63, wave = tid >> 6;
  const float* xr = x + (size_t)blockIdx.x * EMBED;
  float4 v = *(const float4*)(xr + tid * 4);
  float vv[4] = {v.x, v.y, v.z, v.w};
  float s  = vv[0] + vv[1] + vv[2] + vv[3];
  float s2 = vv[0]*vv[0] + vv[1]*vv[1] + vv[2]*vv[2] + vv[3]*vv[3];
  #pragma unroll
  for (int off = 32; off >= 1; off >>= 1) {
    s  += __shfl_xor(s, off);
    s2 += __shfl_xor(s2, off);
  }
  if (lane == 0) { red[wave] = s; red[4 + wave] = s2; }
  __syncthreads();
  s  = red[0] + red[1] + red[2] + red[3];
  s2 = red[4] + red[5] + red[6] + red[7];
  const float mu  = s * (1.f / EMBED);
  const float var = s2 * (1.f / EMBED) - mu * mu;
  const float rs  = rsqrtf(fmaxf(var, 0.f) + 1e-5f);
  #pragma unroll
  for (int i = 0; i < 4; ++i) {
    const int col = tid * 4 + i;
    const float o = (vv[i] - mu) * rs * g[col] + b[col];
    const size_t idx = (size_t)blockIdx.x * EMBED + col;
    if (out_b) out_b[idx] = (bf16)o;
    if (out_f) out_f[idx] = o;
  }
}

// ---------------------------------------------------------------------------
// MFMA flash attention, 128-q tile per block (4 waves x 2 m-tiles), 64-key
// K-tiles.  K/V staged via global_load_lds (linear dest + inverse-swizzled
// source + swizzled read), double-buffered with prefetch-before-compute.
// SWAPPED QK^T (mfma(K,Q)): S^T layout puts a q-row's 64 keys into 16
// in-lane values x 4 quads -> softmax reduction is 15 in-lane ops + 2
// shuffles (was 16 shuffles), m/l state is 1 scalar per m-tile, and P
// stores vectorize to ds_write_b64.  PV unchanged (P round-trips via LDS).
// ---------------------------------------------------------------------------
__global__ __launch_bounds__(256) void fattn_kernel(
    const bf16* __restrict__ Q, int ldq, const bf16* __restrict__ K, int ldk,
    const bf16* __restrict__ Vt, bf16* __restrict__ Y, int Skv, int causal)
{
  constexpr int PLD = 72;                       // P-buffer stride (conflict-free)
  __shared__ __align__(16) bf16 Ks[2][64 * 64]; // [key][d], swizzled
  __shared__ __align__(16) bf16 Vs[2][64 * 64]; // [d][key], swizzled
  __shared__ __align__(16) bf16 Ps[4 * 32 * PLD];

  const int tid  = threadIdx.x;
  const int lane = tid & 63, wave = tid >> 6;
  const int quad = lane >> 4, l16 = lane & 15;
  const int q0 = blockIdx.x * 128;
  const int bh = blockIdx.y, b = bh >> 4, h = bh & 15;
  const int wq0 = q0 + wave * 32;

  const bf16* Kb = K + (size_t)b * Skv * ldk + h * HDIM;
  const bf16* Vb = Vt + (size_t)(bh * HDIM) * Skv;

  // staging lane geometry: lane l -> row r0+(l>>3), dest 16B-block (l&7);
  // source block = dest ^ (row&7)  (row&7 == l>>3)
  const int sr = lane >> 3;
  const int se = ((lane & 7) ^ sr) << 3;        // swizzled source elem offset

  // swizzled read offsets (row&7 == l16&7 since nt*16 is a multiple of 8)
  const int sw  = l16 & 7;
  const int co0 = (quad ^ sw) << 3;             // block quad   -> elems quad*8
  const int co1 = ((4 + quad) ^ sw) << 3;       // block 4+quad -> elems 32+quad*8

  auto stage = [&](int kt, int buf) {
    const int k0 = kt * 64;
    const int r0 = wave * 16;
    gll16(Kb + (size_t)(k0 + r0 + sr) * ldk + se,     &Ks[buf][(r0)     * 64]);
    gll16(Kb + (size_t)(k0 + r0 + 8 + sr) * ldk + se, &Ks[buf][(r0 + 8) * 64]);
    gll16(Vb + (size_t)(r0 + sr) * Skv + k0 + se,     &Vs[buf][(r0)     * 64]);
    gll16(Vb + (size_t)(r0 + 8 + sr) * Skv + k0 + se, &Vs[buf][(r0 + 8) * 64]);
  };

  bf16x8 qf[2][2];
  #pragma unroll
  for (int i = 0; i < 2; ++i) {
    const bf16* qp = Q + (size_t)(b * SEQ + wq0 + i * 16 + l16) * ldq + h * HDIM;
    qf[i][0] = *(const bf16x8*)(qp + quad * 8);
    qf[i][1] = *(const bf16x8*)(qp + 32 + quad * 8);
  }

  f32x4 O[2][4];
  float m_run[2], l_run[2];
  #pragma unroll
  for (int i = 0; i < 2; ++i)
    #pragma unroll
    for (int nt = 0; nt < 4; ++nt) O[i][nt] = f32x4{0, 0, 0, 0};
  #pragma unroll
  for (int i = 0; i < 2; ++i) { m_run[i] = -1e30f; l_run[i] = 0.f; }

  bf16* Pw = Ps + wave * 32 * PLD;
  const int nkt = causal ? (q0 / 64 + 2) : (Skv / 64);

  stage(0, 0);
  __syncthreads();          // tile 0 landed (vmcnt(0) + barrier)

  for (int kt = 0; kt < nkt; ++kt) {
    const int cur = kt & 1;
    const int k0 = kt * 64;
    if (kt + 1 < nkt) stage(kt + 1, cur ^ 1);   // prefetch overlaps compute

    const bf16* Kc = Ks[cur];
    const bf16* Vc = Vs[cur];

    // ---- S^T = K Q^T  (swapped operands: col=l16 -> q, row=quad*4+r -> key)
    f32x4 s[2][4];
    __builtin_amdgcn_s_setprio(1);
    #pragma unroll
    for (int nt = 0; nt < 4; ++nt) {
      const int row = nt * 16 + l16;
      bf16x8 kf0 = *(const bf16x8*)(Kc + row * 64 + co0);
      bf16x8 kf1 = *(const bf16x8*)(Kc + row * 64 + co1);
      #pragma unroll
      for (int i = 0; i < 2; ++i) {
        f32x4 t = f32x4{0, 0, 0, 0};
        t = __builtin_amdgcn_mfma_f32_16x16x32_bf16(kf0, qf[i][0], t, 0, 0, 0);
        t = __builtin_amdgcn_mfma_f32_16x16x32_bf16(kf1, qf[i][1], t, 0, 0, 0);
        s[i][nt] = t;
      }
    }
    __builtin_amdgcn_s_setprio(0);

    const bool diag = causal && (k0 + 63 > wq0);
    #pragma unroll
    for (int i = 0; i < 2; ++i) {
      const int q = wq0 + i * 16 + l16;
      #pragma unroll
      for (int nt = 0; nt < 4; ++nt) {
        #pragma unroll
        for (int r = 0; r < 4; ++r) {
          float v = s[i][nt][r] * 0.125f;          // 1/sqrt(64)
          const int key = k0 + nt * 16 + quad * 4 + r;
          if (diag && key > q) v = -1e30f;
          s[i][nt][r] = v;
        }
      }
    }

    // ---- online softmax (per q-row state lives at lane l16, uniform over quads)
    #pragma unroll
    for (int i = 0; i < 2; ++i) {
      float pm = s[i][0][0];
      #pragma unroll
      for (int nt = 0; nt < 4; ++nt)
        #pragma unroll
        for (int r = 0; r < 4; ++r) pm = fmaxf(pm, s[i][nt][r]);
      pm = fmaxf(pm, __shfl_xor(pm, 16));
      pm = fmaxf(pm, __shfl_xor(pm, 32));
      const float m_new = fmaxf(m_run[i], pm);
      const float al = __expf(m_run[i] - m_new);
      m_run[i] = m_new;
      float ls = 0.f;
      #pragma unroll
      for (int nt = 0; nt < 4; ++nt) {
        #pragma unroll
        for (int r = 0; r < 4; ++r) {
          const float e = __expf(s[i][nt][r] - m_new);
          s[i][nt][r] = e;
          ls += e;
        }
      }
      ls += __shfl_xor(ls, 16);
      ls += __shfl_xor(ls, 32);
      l_run[i] = l_run[i] * al + ls;
      // P store: row q=i*16+l16, keys nt*16+quad*4..+3 contiguous -> b64
      #pragma unroll
      for (int nt = 0; nt < 4; ++nt) {
        bf16x4 pk;
        pk[0] = (bf16)s[i][nt][0]; pk[1] = (bf16)s[i][nt][1];
        pk[2] = (bf16)s[i][nt][2]; pk[3] = (bf16)s[i][nt][3];
        *(bf16x4*)(Pw + (i * 16 + l16) * PLD + nt * 16 + quad * 4) = pk;
      }
      // O rescale: O rows are quad*4+r -> pull al from lane (quad*4+r)
      float alo[4];
      #pragma unroll
      for (int r = 0; r < 4; ++r) alo[r] = __shfl(al, quad * 4 + r);
      #pragma unroll
      for (int nt = 0; nt < 4; ++nt)
        #pragma unroll
        for (int r = 0; r < 4; ++r) O[i][nt][r] *= alo[r];
    }

    // ---- O += P V ----
    bf16x8 pf[2][2];
    #pragma unroll
    for (int i = 0; i < 2; ++i) {
      pf[i][0] = *(const bf16x8*)(Pw + (i * 16 + l16) * PLD + quad * 8);
      pf[i][1] = *(const bf16x8*)(Pw + (i * 16 + l16) * PLD + 32 + quad * 8);
    }
    __builtin_amdgcn_s_setprio(1);
    #pragma unroll
    for (int nt = 0; nt < 4; ++nt) {
      const int row = nt * 16 + l16;
      bf16x8 vf0 = *(const bf16x8*)(Vc + row * 64 + co0);
      bf16x8 vf1 = *(const bf16x8*)(Vc + row * 64 + co1);
      #pragma unroll
      for (int i = 0; i < 2; ++i) {
        O[i][nt] = __builtin_amdgcn_mfma_f32_16x16x32_bf16(pf[i][0], vf0, O[i][nt], 0, 0, 0);
        O[i][nt] = __builtin_amdgcn_mfma_f32_16x16x32_bf16(pf[i][1], vf1, O[i][nt], 0, 0, 0);
      }
    }
    __builtin_amdgcn_s_setprio(0);
    __syncthreads();        // all reads of buf[cur] done; next-tile DMA drained
  }

  #pragma unroll
  for (int i = 0; i < 2; ++i) {
    float inv[4];
    #pragma unroll
    for (int r = 0; r < 4; ++r) {
      const float lv = __shfl(l_run[i], quad * 4 + r);
      inv[r] = 1.f / lv;
    }
    #pragma unroll
    for (int nt = 0; nt < 4; ++nt) {
      #pragma unroll
      for (int r = 0; r < 4; ++r) {
        const int q = wq0 + i * 16 + quad * 4 + r;
        Y[((size_t)(b * SEQ + q)) * EMBED + h * HDIM + nt * 16 + l16] = (bf16)(O[i][nt][r] * inv[r]);
      }
    }
  }
}

__global__ void fill_kernel(float* out, float v, int n) {
  int i = blockIdx.x * 256 + threadIdx.x;
  if (i < n) out[i] = v;
}

// ---------------------------------------------------------------------------
extern "C" void kernel_launch(void* const* d_in, const int* in_sizes, int n_in,
                              void* d_out, int out_size, void* d_ws, size_t ws_size,
                              hipStream_t stream)
{
  const float* tgt    = (const float*)d_in[0];
  const float* mem    = (const float*)d_in[1];
  const float* sa_Wq  = (const float*)d_in[3];
  const float* sa_Wqb = (const float*)d_in[4];
  const float* sa_Wk  = (const float*)d_in[5];
  const float* sa_Wkb = (const float*)d_in[6];
  const float* sa_Wv  = (const float*)d_in[7];
  const float* sa_Wvb = (const float*)d_in[8];
  const float* sa_A   = (const float*)d_in[9];
  const float* sa_Ab  = (const float*)d_in[10];
  const float* ca_Wq  = (const float*)d_in[11];
  const float* ca_Wqb = (const float*)d_in[12];
  const float* ca_Wk  = (const float*)d_in[13];
  const float* ca_Wkb = (const float*)d_in[14];
  const float* ca_Wv  = (const float*)d_in[15];
  const float* ca_Wvb = (const float*)d_in[16];
  const float* ca_A   = (const float*)d_in[17];
  const float* ca_Ab  = (const float*)d_in[18];
  const float* l1W    = (const float*)d_in[19];
  const float* l1b    = (const float*)d_in[20];
  const float* l2W    = (const float*)d_in[21];
  const float* l2b    = (const float*)d_in[22];
  const float* g1     = (const float*)d_in[23];
  const float* b1     = (const float*)d_in[24];
  const float* g2     = (const float*)d_in[25];
  const float* b2     = (const float*)d_in[26];
  const float* g3     = (const float*)d_in[27];
  const float* b3     = (const float*)d_in[28];

  const size_t MB = 1024 * 1024;
  const size_t NEED = 80 * MB + 4096;
  if (ws_size < NEED) {
    fill_kernel<<<(out_size + 255) / 256, 256, 0, stream>>>((float*)d_out, 3.0f, out_size);
    return;
  }

  char* ws = (char*)d_ws;
  const size_t MD = (size_t)MROWS * EMBED;       // 8M elements
  // phase A
  bf16*  qkv   = (bf16*)ws;                      // [8192][3072] 48 MB
  bf16*  yb    = (bf16*)(ws + 48 * MB);          // 16 MB attention output
  bf16*  wqkvt = (bf16*)(ws + 48 * MB);          // 6 MB weights (dead before fattn writes yb)
  float* qkvbias = (float*)(ws + 54 * MB + 512 * 1024);
  // phase B
  bf16*  kvb   = (bf16*)ws;                      // [8192][2048] 32 MB
  bf16*  qB    = (bf16*)(ws + 32 * MB);          // 16 MB
  bf16*  wkvt  = (bf16*)(ws + 48 * MB);          // 4 MB
  bf16*  wqt   = (bf16*)(ws + 52 * MB);          // 2 MB
  float* kvbias = (float*)(ws + 54 * MB + 512 * 1024);
  // shared
  bf16*  awt   = (bf16*)ws;                      // 2 MB out-proj Wt (qkv/kvb dead)
  bf16*  xb    = (bf16*)(ws + 64 * MB);          // 16 MB LN output stream
  // phase C
  bf16*  hb    = (bf16*)ws;                      // [8192][2048] 32 MB hidden half
  bf16*  l1t   = (bf16*)(ws + 32 * MB);          // 8 MB
  bf16*  l2t   = (bf16*)(ws + 40 * MB);          // 8 MB
  // d_out regions
  float* P   = (float*)d_out;                    // fp32 pre-LN scratch (32 MB)
  bf16*  inb = (bf16*)d_out;                     // converted tgt/mem (16 MB)
  bf16*  vtg = (bf16*)((char*)d_out + 16 * MB);  // V^T for attention (16 MB)

  dim3 blk(256);
  dim3 gQKV(3072 / 128, MROWS / 128);   // (24,64)
  dim3 gKV(2048 / 128, MROWS / 128);    // (16,64)
  dim3 gEE(EMBED / 128, MROWS / 128);   // (8,64)
  dim3 gF1(2048 / 128, MROWS / 128);    // (16,64)
  dim3 gAT(SEQ / 128, BATCH * HEADS);   // (16,64)
  dim3 gVT(SEQ / 64, BATCH * HEADS);    // (32,64)
  dim3 gWee(16, 16);
  const int ncv = (int)(MD / 8 / 256);

  // ---- Phase A: self-attention ----
  cvt_kernel<<<ncv, blk, 0, stream>>>(tgt, inb, (int)MD);
  wt_kernel<<<gWee, blk, 0, stream>>>(sa_Wq, wqkvt, EMBED, EMBED);
  wt_kernel<<<gWee, blk, 0, stream>>>(sa_Wk, wqkvt + 1024 * 1024, EMBED, EMBED);
  wt_kernel<<<gWee, blk, 0, stream>>>(sa_Wv, wqkvt + 2 * 1024 * 1024, EMBED, EMBED);
  cat3_kernel<<<12, blk, 0, stream>>>(qkvbias, sa_Wqb, sa_Wkb, sa_Wvb, EMBED);
  gemm128<<<gQKV, blk, 0, stream>>>(inb, EMBED, wqkvt, EMBED, qkvbias, nullptr, nullptr, qkv, nullptr, 3072, EMBED, 0);
  vtr_kernel<<<gVT, blk, 0, stream>>>(qkv + 2048, 3072, vtg, SEQ);
  fattn_kernel<<<gAT, blk, 0, stream>>>(qkv, 3072, qkv + 1024, 3072, vtg, yb, SEQ, 1);
  wt_kernel<<<gWee, blk, 0, stream>>>(sa_A, awt, EMBED, EMBED);
  gemm128<<<gEE, blk, 0, stream>>>(yb, EMBED, awt, EMBED, sa_Ab, nullptr, tgt, nullptr, P, EMBED, EMBED, 0);
  ln_kernel<<<MROWS, blk, 0, stream>>>(P, g1, b1, xb, nullptr);

  // ---- Phase B: cross-attention ----
  cvt_kernel<<<ncv, blk, 0, stream>>>(mem, inb, (int)MD);
  wt_kernel<<<gWee, blk, 0, stream>>>(ca_Wk, wkvt, EMBED, EMBED);
  wt_kernel<<<gWee, blk, 0, stream>>>(ca_Wv, wkvt + 1024 * 1024, EMBED, EMBED);
  wt_kernel<<<gWee, blk, 0, stream>>>(ca_Wq, wqt, EMBED, EMBED);
  cat3_kernel<<<8, blk, 0, stream>>>(kvbias, ca_Wkb, ca_Wvb, nullptr, EMBED);
  gemm128<<<gKV, blk, 0, stream>>>(inb, EMBED, wkvt, EMBED, kvbias, nullptr, nullptr, kvb, nullptr, 2048, EMBED, 0);
  gemm128<<<gEE, blk, 0, stream>>>(xb, EMBED, wqt, EMBED, ca_Wqb, nullptr, nullptr, qB, nullptr, EMBED, EMBED, 0);
  vtr_kernel<<<gVT, blk, 0, stream>>>(kvb + 1024, 2048, vtg, SEQ);
  fattn_kernel<<<gAT, blk, 0, stream>>>(qB, 1024, kvb, 2048, vtg, yb, SEQ, 0);
  wt_kernel<<<gWee, blk, 0, stream>>>(ca_A, awt, EMBED, EMBED);
  gemm128<<<gEE, blk, 0, stream>>>(yb, EMBED, awt, EMBED, ca_Ab, xb, nullptr, nullptr, P, EMBED, EMBED, 0);
  ln_kernel<<<MROWS, blk, 0, stream>>>(P, g2, b2, xb, nullptr);

  // ---- Phase C: FFN (split-K over DFF halves) ----
  wt_kernel<<<dim3(16, 64), blk, 0, stream>>>(l1W, l1t, EMBED, DFF);
  wt_kernel<<<dim3(64, 16), blk, 0, stream>>>(l2W, l2t, DFF, EMBED);
  gemm128<<<gF1, blk, 0, stream>>>(xb, EMBED, l1t, EMBED, l1b, nullptr, nullptr, hb, nullptr, 2048, EMBED, 1);
  gemm128<<<gEE, blk, 0, stream>>>(hb, 2048, l2t, DFF, l2b, xb, nullptr, nullptr, P, EMBED, 2048, 0);
  gemm128<<<gF1, blk, 0, stream>>>(xb, EMBED, l1t + (size_t)2048 * 1024, EMBED, l1b + 2048, nullptr, nullptr, hb, nullptr, 2048, EMBED, 1);
  gemm128<<<gEE, blk, 0, stream>>>(hb, 2048, l2t + 2048, DFF, nullptr, nullptr, P, nullptr, P, EMBED, 2048, 0);
  ln_kernel<<<MROWS, blk, 0, stream>>>(P, g3, b3, nullptr, (float*)d_out);
}